// Round 9
// baseline (275.116 us; speedup 1.0000x reference)
//
#include <hip/hip_runtime.h>

#define IMG_W 512
#define IMG_H 512
#define PLANE_PX (IMG_W * IMG_H)
#define N_ELEMS (48 * PLANE_PX)
#define NTHREADS 256
#define NBLK 1280             // 5 blocks/CU exactly (LDS 32768 B each)
#define SPW 6                 // strips per wave-slot: 30720 waves / 5120 slots

#define C1f 1.0e-4f
#define C2f 9.0e-4f

typedef float v2f __attribute__((ext_vector_type(2)));

// Packed fp32 FMA (v_pk_fma_f32).
__device__ __forceinline__ v2f pkfma(float w, v2f v, v2f acc) {
    v2f wv = {w, w};
    return __builtin_elementwise_fma(wv, v, acc);
}

__global__ void __launch_bounds__(NTHREADS, 5) ssim_main(
    const float* __restrict__ img1, const float* __restrict__ img2,
    float* __restrict__ partials)
{
    // Per-wave PRIVATE scratch: V[wave][k=8 rows][c=64 cols], float4 =
    // (conv_s, conv_d, conv_ss, conv_dd). 4 x 8KB = 32768 B -> 5 blocks/CU.
    __shared__ float4 V[2048];

    constexpr float G[11] = {
        0.00102838f, 0.00759876f, 0.03600077f, 0.10936070f, 0.21300553f,
        0.26601173f,
        0.21300553f, 0.10936070f, 0.03600077f, 0.00759876f, 0.00102838f
    };

    const int tid = threadIdx.x;
    const int lane = tid & 63;
    const int wv = tid >> 6;
    float4* Vw = V + wv * 512;

    // Work mapping: XCD (blockIdx&7) owns 6 planes; slot in [0,640) =
    // (band, scol); iteration = plane. One wave = one 54x8 strip.
    const int xcd = blockIdx.x & 7;
    const int slot = (blockIdx.x >> 3) * 4 + wv;       // [0,640)
    const int band = slot / 10;                        // [0,64) -> rows 8b..8b+8
    const int scol = slot - band * 10;                 // [0,10) -> cols 54s..
    const int ry0 = band * 8 - 5;
    const bool interior = (band >= 1) & (band <= 62);  // wave-uniform

    // Phase A: lane owns staged column gx (zero-pad via mask, applied to acc
    // once per strip -- conv is linear and ml in {0,1} so ml^2 == ml).
    const int gx = scol * 54 - 5 + lane;
    const int cgx = min(max(gx, 0), IMG_W - 1);
    const float ml = ((unsigned)gx < (unsigned)IMG_W) ? 1.f : 0.f;
    const v2f mlv = {ml, ml};

    // Phase B: lane = (krow kq, col-group cg of 7 outputs).
    const int kq = lane >> 3;
    const int cg = lane & 7;
    const int c0 = cg * 7;                 // 0,7,...,49: distinct bank-octants
    const bool cglt7 = (cg < 7);           // cg==7 has only 5 valid outputs

    float local = 0.f;

    for (int it = 0; it < SPW; ++it) {
        const int plane = xcd * SPW + it;
        const float* pa = img1 + (size_t)plane * PLANE_PX + cgx;
        const float* pb = img2 + (size_t)plane * PLANE_PX + cgx;

        // ---- Phase A: vertical conv down own column (coalesced row loads) ----
        v2f asd[8], asq[8];
#pragma unroll
        for (int kk = 0; kk < 8; ++kk) { asd[kk] = (v2f)0.f; asq[kk] = (v2f)0.f; }

        if (interior) {
#pragma unroll
            for (int j = 0; j < 18; ++j) {
                float a = pa[(ry0 + j) * IMG_W];       // 256B coalesced
                float b = pb[(ry0 + j) * IMG_W];
                v2f sd; sd.x = a + b; sd.y = a - b;
                v2f sq = sd * sd;
#pragma unroll
                for (int kk = 0; kk < 8; ++kk) {
                    int t = j - kk;
                    if (t >= 0 && t < 11) {            // folds at compile time
                        asd[kk] = pkfma(G[t], sd, asd[kk]);
                        asq[kk] = pkfma(G[t], sq, asq[kk]);
                    }
                }
            }
        } else {
#pragma unroll
            for (int j = 0; j < 18; ++j) {
                int ry = ry0 + j;                      // scalar
                int ryc = min(max(ry, 0), IMG_H - 1);
                float rm = ((unsigned)ry < (unsigned)IMG_H) ? 1.f : 0.f;
                float a = pa[ryc * IMG_W] * rm;
                float b = pb[ryc * IMG_W] * rm;
                v2f sd; sd.x = a + b; sd.y = a - b;
                v2f sq = sd * sd;
#pragma unroll
                for (int kk = 0; kk < 8; ++kk) {
                    int t = j - kk;
                    if (t >= 0 && t < 11) {
                        asd[kk] = pkfma(G[t], sd, asd[kk]);
                        asq[kk] = pkfma(G[t], sq, asq[kk]);
                    }
                }
            }
        }

#pragma unroll
        for (int kk = 0; kk < 8; ++kk) {
            v2f wsd = asd[kk] * mlv;                   // apply column mask once
            v2f wsq = asq[kk] * mlv;
            Vw[kk * 64 + lane] = make_float4(wsd.x, wsd.y, wsq.x, wsq.y);
        }
        // Same-wave LDS write->read is in-order: NO barrier.

        // ---- Phase B: horizontal conv on own krow from private LDS ----
        v2f osd[7], osq[7];
#pragma unroll
        for (int o = 0; o < 7; ++o) { osd[o] = (v2f)0.f; osq[o] = (v2f)0.f; }

        const float4* row = Vw + kq * 64;
#pragma unroll
        for (int j = 0; j < 17; ++j) {
            // j<15 always in-bounds (c0+j<=63); j=15,16 clamp (only cg==7
            // would overrun, and those taps feed its masked outputs only).
            int cidx = (j < 15) ? (c0 + j) : min(c0 + j, 63);
            float4 v = row[cidx];                      // ds_read_b128
            v2f vsd; vsd.x = v.x; vsd.y = v.y;
            v2f vsq; vsq.x = v.z; vsq.y = v.w;
#pragma unroll
            for (int o = 0; o < 7; ++o) {
                int t = j - o;
                if (t >= 0 && t < 11) {
                    osd[o] = pkfma(G[t], vsd, osd[o]);
                    osq[o] = pkfma(G[t], vsq, osq[o]);
                }
            }
        }

        // ---- Epilogue: SSIM per output px + masked accumulate ----
        const int gxo0 = scol * 54 + c0;
#pragma unroll
        for (int o = 0; o < 7; ++o) {
            v2f s2 = osd[o] * osd[o];
            float cs2 = s2.x, cd2 = s2.y;
            float css = osq[o].x, cdd = osq[o].y;
            float mu12 = 0.25f * (cs2 - cd2);          // mu1*mu2
            float musq = 0.50f * (cs2 + cd2);          // mu1^2+mu2^2
            float e12  = 0.25f * (css - cdd);          // E[ab]
            float esum = 0.50f * (css + cdd);          // E[a^2]+E[b^2]
            float num = (2.f * mu12 + C1f) * (2.f * (e12 - mu12) + C2f);
            float den = (musq + C1f) * ((esum - musq) + C2f);
            float sv = num * __builtin_amdgcn_rcpf(den);
            // valid: cg<7 -> o in [0,7); cg==7 -> o in [0,5); plus x<512.
            bool valid = (gxo0 + o < IMG_W) && (o < 5 || cglt7);
            local += valid ? sv : 0.f;
        }
    }

    // ---- Reduction: wave shuffle -> partial via own LDS region -> block ----
#pragma unroll
    for (int off = 32; off > 0; off >>= 1) local += __shfl_down(local, off, 64);
    if (lane == 0) ((float*)Vw)[0] = local;            // own region: no race
    __syncthreads();
    if (tid == 0) {
        const float* Vf = (const float*)V;
        partials[blockIdx.x] = Vf[0] + Vf[2048] + Vf[4096] + Vf[6144];
    }
}

__global__ void ssim_final(const float* __restrict__ partials,
                           float* __restrict__ out)
{
    __shared__ float wp[4];
    const int tid = threadIdx.x;
    const float4* p4 = (const float4*)partials;        // NBLK/4 = 320
    float s = 0.f;
    for (int i = tid; i < NBLK / 4; i += NTHREADS) {
        float4 v = p4[i];
        s += (v.x + v.y) + (v.z + v.w);
    }
#pragma unroll
    for (int off = 32; off > 0; off >>= 1) s += __shfl_down(s, off, 64);
    if ((tid & 63) == 0) wp[tid >> 6] = s;
    __syncthreads();
    if (tid == 0)
        out[0] = 1.0f - (wp[0] + wp[1] + wp[2] + wp[3]) * (1.0f / (float)N_ELEMS);
}

extern "C" void kernel_launch(void* const* d_in, const int* in_sizes, int n_in,
                              void* d_out, int out_size, void* d_ws, size_t ws_size,
                              hipStream_t stream) {
    const float* img1 = (const float*)d_in[0];
    const float* img2 = (const float*)d_in[1];
    float* out = (float*)d_out;
    float* partials = (float*)d_ws;     // NBLK floats = 5 KB

    ssim_main<<<NBLK, NTHREADS, 0, stream>>>(img1, img2, partials);
    ssim_final<<<1, NTHREADS, 0, stream>>>(partials, out);
}

// Round 10
// 138.343 us; speedup vs baseline: 1.9887x; 1.9887x over previous
//
#include <hip/hip_runtime.h>

#define IMG_W 512
#define IMG_H 512
#define PLANE_PX (IMG_W * IMG_H)
#define N_ELEMS (48 * PLANE_PX)
#define NTHREADS 256
#define TILEW 54
#define NCT 10                 // 9 full col-tiles + 1 partial (26)
#define NBLK (48 * 16 * NCT)   // 7680
#define RSTR 68                // r row stride in uint2 (64 used; rotates banks)

#define C1f 1.0e-4f
#define C2f 9.0e-4f

typedef float v2f __attribute__((ext_vector_type(2)));

// Packed fp32 FMA (v_pk_fma_f32 on gfx950).
__device__ __forceinline__ v2f pkfma(float w, v2f v, v2f acc) {
    v2f wv = {w, w};
    return __builtin_elementwise_fma(wv, v, acc);
}

// Pack two fp32 -> bf16 pair: lo16 = bf16(x), hi16 = bf16(y). (R6-verified.)
__device__ __forceinline__ unsigned int pk2bf(float x, float y) {
    unsigned int ax = __float_as_uint(x) + 0x8000u;
    unsigned int by = __float_as_uint(y) + 0x8000u;
    return __builtin_amdgcn_perm(by, ax, 0x07060302);
}

__global__ void __launch_bounds__(NTHREADS, 6) ssim_main(
    const float* __restrict__ img1, const float* __restrict__ img2,
    float* __restrict__ partials)
{
    // Vertical-conv results, bf16 pairs: R[row][col] = (bf16(cs),bf16(cd) | bf16(css),bf16(cdd))
    __shared__ uint2 R[32 * RSTR];          // 17408 B
    __shared__ float wpart[4];

    constexpr float G[11] = {
        0.00102838f, 0.00759876f, 0.03600077f, 0.10936070f, 0.21300553f,
        0.26601173f,
        0.21300553f, 0.10936070f, 0.03600077f, 0.00759876f, 0.00102838f
    };

    const int tid = threadIdx.x;

    // Work decode + XCD swizzle: XCD (blockIdx&7) owns 6 contiguous planes.
    const int xcd = blockIdx.x & 7;
    const int idx = blockIdx.x >> 3;             // [0,960)
    const int plane = xcd * 6 + idx / 160;
    const int t = idx % 160;
    const int band = t / 10;                     // y-band [0,16), 32 rows each
    const int ct = t - band * 10;                // col-tile [0,10)
    const int tx0 = ct * TILEW;
    const int ty0 = band * 32;
    const float* pa = img1 + (size_t)plane * PLANE_PX;
    const float* pb = img2 + (size_t)plane * PLANE_PX;

    // ================= Phase A: vertical conv, lane = staged column =========
    // 64 cols x 4 row-groups (one wave each): ALL lanes of ALL waves active.
    const int c = tid & 63;                      // staged col
    const int g = tid >> 6;                      // wave = row-group
    const int gx = tx0 - 5 + c;
    const int cgx = min(max(gx, 0), IMG_W - 1);
    const float ml = ((unsigned)gx < (unsigned)IMG_W) ? 1.f : 0.f;
    const int ry0 = ty0 + g * 8 - 5;

    // Batch ALL 36 loads first (coalesced 256B rows; deep MLP).
    float av[18], bv[18];
    const bool intY = (ry0 >= 0) && (ry0 + 18 <= IMG_H);     // wave-uniform
    if (intY) {
        const float* qa = pa + (size_t)ry0 * IMG_W + cgx;
        const float* qb = pb + (size_t)ry0 * IMG_W + cgx;
#pragma unroll
        for (int j = 0; j < 18; ++j) {
            av[j] = qa[j * IMG_W];
            bv[j] = qb[j * IMG_W];
        }
    } else {
#pragma unroll
        for (int j = 0; j < 18; ++j) {
            int ry = ry0 + j;
            int ryc = min(max(ry, 0), IMG_H - 1);
            float rm = ((unsigned)ry < (unsigned)IMG_H) ? 1.f : 0.f;
            av[j] = pa[(size_t)ryc * IMG_W + cgx] * rm;
            bv[j] = pb[(size_t)ryc * IMG_W + cgx] * rm;
        }
    }

    v2f asd[8], asq[8];
#pragma unroll
    for (int k = 0; k < 8; ++k) { asd[k] = (v2f)0.f; asq[k] = (v2f)0.f; }
#pragma unroll
    for (int j = 0; j < 18; ++j) {
        v2f sd; sd.x = av[j] + bv[j]; sd.y = av[j] - bv[j];
        v2f sq = sd * sd;
#pragma unroll
        for (int k = 0; k < 8; ++k) {
            int tt = j - k;
            if (tt >= 0 && tt < 11) {            // folds at compile time
                asd[k] = pkfma(G[tt], sd, asd[k]);
                asq[k] = pkfma(G[tt], sq, asq[k]);
            }
        }
    }
#pragma unroll
    for (int k = 0; k < 8; ++k) {
        // Column mask applied once (conv is linear; ml in {0,1}).
        float sx = asd[k].x * ml, sy = asd[k].y * ml;
        float qx = asq[k].x * ml, qy = asq[k].y * ml;
        R[(g * 8 + k) * RSTR + c] = make_uint2(pk2bf(sx, sy), pk2bf(qx, qy));
    }
    __syncthreads();

    // ================= Phase B: horizontal conv + SSIM =======================
    // 32 rows x 8 col-groups x 7 outputs: all lanes active (cg=7: 5 valid).
    const int y = tid >> 3;
    const int cg = tid & 7;
    const int c0 = cg * 7;
    const uint2* row = R + y * RSTR;

    v2f osd[7], osq[7];
#pragma unroll
    for (int o = 0; o < 7; ++o) { osd[o] = (v2f)0.f; osq[o] = (v2f)0.f; }

#pragma unroll
    for (int j = 0; j < 17; ++j) {
        // j>=15 only matters for cg==7, whose o>=5 outputs are masked: clamp.
        int cidx = (j < 15) ? (c0 + j) : min(c0 + j, 63);
        uint2 p = row[cidx];                     // ds_read_b64
        v2f vsd, vsq;
        vsd.x = __uint_as_float(p.x << 16);
        vsd.y = __uint_as_float(p.x & 0xffff0000u);
        vsq.x = __uint_as_float(p.y << 16);
        vsq.y = __uint_as_float(p.y & 0xffff0000u);
#pragma unroll
        for (int o = 0; o < 7; ++o) {
            int tt = j - o;
            if (tt >= 0 && tt < 11) {
                osd[o] = pkfma(G[tt], vsd, osd[o]);
                osq[o] = pkfma(G[tt], vsq, osq[o]);
            }
        }
    }

    float local = 0.f;
#pragma unroll
    for (int o = 0; o < 7; ++o) {
        v2f s2 = osd[o] * osd[o];
        float cs2 = s2.x, cd2 = s2.y;
        float css = osq[o].x, cdd = osq[o].y;
        float mu12 = 0.25f * (cs2 - cd2);        // mu1*mu2
        float musq = 0.50f * (cs2 + cd2);        // mu1^2 + mu2^2
        float e12  = 0.25f * (css - cdd);        // E[ab]
        float esum = 0.50f * (css + cdd);        // E[a^2] + E[b^2]
        float num = (2.f * mu12 + C1f) * (2.f * (e12 - mu12) + C2f);
        float den = (musq + C1f) * ((esum - musq) + C2f);
        float sv = num * __builtin_amdgcn_rcpf(den);
        bool valid = (c0 + o < TILEW) && (tx0 + c0 + o < IMG_W);
        local += valid ? sv : 0.f;
    }

    // ================= Block reduction -> one partial ========================
#pragma unroll
    for (int off = 32; off > 0; off >>= 1) local += __shfl_down(local, off, 64);
    if ((tid & 63) == 0) wpart[tid >> 6] = local;
    __syncthreads();
    if (tid == 0)
        partials[blockIdx.x] = wpart[0] + wpart[1] + wpart[2] + wpart[3];
}

__global__ void ssim_final(const float* __restrict__ partials,
                           float* __restrict__ out)
{
    __shared__ float wp[4];
    const int tid = threadIdx.x;
    const float4* p4 = (const float4*)partials;  // 7680/4 = 1920 float4
    float s = 0.f;
    for (int i = tid; i < NBLK / 4; i += NTHREADS) {
        float4 v = p4[i];
        s += (v.x + v.y) + (v.z + v.w);
    }
#pragma unroll
    for (int off = 32; off > 0; off >>= 1) s += __shfl_down(s, off, 64);
    if ((tid & 63) == 0) wp[tid >> 6] = s;
    __syncthreads();
    if (tid == 0)
        out[0] = 1.0f - (wp[0] + wp[1] + wp[2] + wp[3]) * (1.0f / (float)N_ELEMS);
}

extern "C" void kernel_launch(void* const* d_in, const int* in_sizes, int n_in,
                              void* d_out, int out_size, void* d_ws, size_t ws_size,
                              hipStream_t stream) {
    const float* img1 = (const float*)d_in[0];
    const float* img2 = (const float*)d_in[1];
    float* out = (float*)d_out;
    float* partials = (float*)d_ws;     // NBLK floats = 30.7 KB

    ssim_main<<<NBLK, NTHREADS, 0, stream>>>(img1, img2, partials);
    ssim_final<<<1, NTHREADS, 0, stream>>>(partials, out);
}

// Round 12
// 133.594 us; speedup vs baseline: 2.0593x; 1.0355x over previous
//
#include <hip/hip_runtime.h>

#define IMG_W 512
#define IMG_H 512
#define PLANE_PX (IMG_W * IMG_H)
#define N_ELEMS (48 * PLANE_PX)
#define NTHREADS 256
#define TILEW 54
#define NCT 10                 // 9 full col-tiles + 1 partial (26)
#define NBLK (48 * 16 * NCT)   // 7680
#define RSTR 66                // R row stride in uint2 (64 used)

#define C1f 1.0e-4f
#define C2f 9.0e-4f

typedef _Float16 h2 __attribute__((ext_vector_type(2)));
typedef __fp16 fp16v2 __attribute__((ext_vector_type(2)));

// Packed f16 FMA (v_pk_fma_f16).
__device__ __forceinline__ h2 h2fma(_Float16 w, h2 v, h2 acc) {
    h2 wv = {w, w};
    return __builtin_elementwise_fma(wv, v, acc);
}
__device__ __forceinline__ unsigned int h2bits(h2 v) {
    union { h2 h; unsigned int u; } c; c.h = v; return c.u;
}
__device__ __forceinline__ h2 bits2h(unsigned int u) {
    union { h2 h; unsigned int u; } c; c.u = u; return c.h;
}
// v_cvt_pkrtz_f16_f32 returns __fp16x2; bit-cast to _Float16x2 (same layout).
__device__ __forceinline__ h2 pkrtz(float x, float y) {
    union { fp16v2 f; h2 h; } c;
    c.f = __builtin_amdgcn_cvt_pkrtz(x, y);
    return c.h;
}

__global__ void __launch_bounds__(NTHREADS, 8) ssim_main(
    const float* __restrict__ img1, const float* __restrict__ img2,
    float* __restrict__ partials)
{
    // Vertical-conv results as packed f16: R[row][col] = {(cs,cd),(css,cdd)}.
    __shared__ uint2 R[32 * RSTR];          // 16896 B -> 8 blocks/CU
    __shared__ float wpart[4];

    // Gaussian window (f16 taps for conv).
    constexpr _Float16 Gh[11] = {
        (_Float16)0.00102838f, (_Float16)0.00759876f, (_Float16)0.03600077f,
        (_Float16)0.10936070f, (_Float16)0.21300553f, (_Float16)0.26601173f,
        (_Float16)0.21300553f, (_Float16)0.10936070f, (_Float16)0.03600077f,
        (_Float16)0.00759876f, (_Float16)0.00102838f
    };

    const int tid = threadIdx.x;

    // Work decode + XCD swizzle: XCD (blockIdx&7) owns 6 contiguous planes.
    const int xcd = blockIdx.x & 7;
    const int idx = blockIdx.x >> 3;             // [0,960)
    const int plane = xcd * 6 + idx / 160;
    const int t = idx % 160;
    const int band = t / 10;                     // y-band [0,16), 32 rows each
    const int ct = t - band * 10;                // col-tile [0,10)
    const int tx0 = ct * TILEW;
    const int ty0 = band * 32;
    const float* pa = img1 + (size_t)plane * PLANE_PX;
    const float* pb = img2 + (size_t)plane * PLANE_PX;

    // ================= Phase A: vertical conv, lane = staged column =========
    const int c = tid & 63;                      // staged col
    const int g = tid >> 6;                      // wave = row-group
    const int gx = tx0 - 5 + c;
    const int cgx = min(max(gx, 0), IMG_W - 1);
    const _Float16 ml = ((unsigned)gx < (unsigned)IMG_W) ? (_Float16)1.f
                                                         : (_Float16)0.f;
    const h2 mlv = {ml, ml};
    const int ry0 = ty0 + g * 8 - 5;

    // Batch all 36 loads (coalesced 256B rows).
    float av[18], bv[18];
    const bool intY = (ry0 >= 0) && (ry0 + 18 <= IMG_H);     // wave-uniform
    if (intY) {
        const float* qa = pa + (size_t)ry0 * IMG_W + cgx;
        const float* qb = pb + (size_t)ry0 * IMG_W + cgx;
#pragma unroll
        for (int j = 0; j < 18; ++j) {
            av[j] = qa[j * IMG_W];
            bv[j] = qb[j * IMG_W];
        }
    } else {
#pragma unroll
        for (int j = 0; j < 18; ++j) {
            int ry = ry0 + j;
            int ryc = min(max(ry, 0), IMG_H - 1);
            float rm = ((unsigned)ry < (unsigned)IMG_H) ? 1.f : 0.f;
            av[j] = pa[(size_t)ryc * IMG_W + cgx] * rm;
            bv[j] = pb[(size_t)ryc * IMG_W + cgx] * rm;
        }
    }

    h2 asd[8], asq[8];
#pragma unroll
    for (int k = 0; k < 8; ++k) { asd[k] = (h2)(_Float16)0; asq[k] = (h2)(_Float16)0; }
#pragma unroll
    for (int j = 0; j < 18; ++j) {
        // (s,d) packed to f16 in ONE inst (v_cvt_pkrtz_f16_f32).
        h2 sd = pkrtz(av[j] + bv[j], av[j] - bv[j]);
        h2 sq = sd * sd;                         // v_pk_mul_f16
#pragma unroll
        for (int k = 0; k < 8; ++k) {
            int tt = j - k;
            if (tt >= 0 && tt < 11) {            // folds at compile time
                asd[k] = h2fma(Gh[tt], sd, asd[k]);
                asq[k] = h2fma(Gh[tt], sq, asq[k]);
            }
        }
    }
#pragma unroll
    for (int k = 0; k < 8; ++k) {
        h2 wsd = asd[k] * mlv;                   // column mask (once, linear)
        h2 wsq = asq[k] * mlv;
        R[(g * 8 + k) * RSTR + c] = make_uint2(h2bits(wsd), h2bits(wsq));
    }
    __syncthreads();

    // ================= Phase B: horizontal conv + SSIM =======================
    // 32 rows x 8 col-groups x 7 outputs; zero unpack (pk_fma_f16 on LDS bits).
    const int y = tid >> 3;
    const int cg = tid & 7;
    const int c0 = cg * 7;
    const uint2* row = R + y * RSTR;

    h2 osd[7], osq[7];
#pragma unroll
    for (int o = 0; o < 7; ++o) { osd[o] = (h2)(_Float16)0; osq[o] = (h2)(_Float16)0; }

#pragma unroll
    for (int j = 0; j < 17; ++j) {
        // c0+j <= 49+16 = 65 < RSTR: cols 64..65 are junk-but-finite and feed
        // only cg==7's masked outputs (o>=5), discarded by `valid` below.
        uint2 p = row[min(c0 + j, 65)];          // ds_read_b64
        h2 vsd = bits2h(p.x);
        h2 vsq = bits2h(p.y);
#pragma unroll
        for (int o = 0; o < 7; ++o) {
            int tt = j - o;
            if (tt >= 0 && tt < 11) {
                osd[o] = h2fma(Gh[tt], vsd, osd[o]);
                osq[o] = h2fma(Gh[tt], vsq, osq[o]);
            }
        }
    }

    float local = 0.f;
#pragma unroll
    for (int o = 0; o < 7; ++o) {
        float cs  = (float)osd[o].x, cd  = (float)osd[o].y;
        float css = (float)osq[o].x, cdd = (float)osq[o].y;
        float cs2 = cs * cs, cd2 = cd * cd;
        float mu12 = 0.25f * (cs2 - cd2);        // mu1*mu2
        float musq = 0.50f * (cs2 + cd2);        // mu1^2 + mu2^2
        float e12  = 0.25f * (css - cdd);        // E[ab]
        float esum = 0.50f * (css + cdd);        // E[a^2] + E[b^2]
        float num = (2.f * mu12 + C1f) * (2.f * (e12 - mu12) + C2f);
        float den = (musq + C1f) * ((esum - musq) + C2f);
        float sv = num * __builtin_amdgcn_rcpf(den);
        bool valid = (c0 + o < TILEW) && (tx0 + c0 + o < IMG_W);
        local += valid ? sv : 0.f;
    }

    // ================= Block reduction -> one partial ========================
#pragma unroll
    for (int off = 32; off > 0; off >>= 1) local += __shfl_down(local, off, 64);
    if ((tid & 63) == 0) wpart[tid >> 6] = local;
    __syncthreads();
    if (tid == 0)
        partials[blockIdx.x] = wpart[0] + wpart[1] + wpart[2] + wpart[3];
}

__global__ void ssim_final(const float* __restrict__ partials,
                           float* __restrict__ out)
{
    __shared__ float wp[4];
    const int tid = threadIdx.x;
    const float4* p4 = (const float4*)partials;  // 7680/4 = 1920 float4
    float s = 0.f;
    for (int i = tid; i < NBLK / 4; i += NTHREADS) {
        float4 v = p4[i];
        s += (v.x + v.y) + (v.z + v.w);
    }
#pragma unroll
    for (int off = 32; off > 0; off >>= 1) s += __shfl_down(s, off, 64);
    if ((tid & 63) == 0) wp[tid >> 6] = s;
    __syncthreads();
    if (tid == 0)
        out[0] = 1.0f - (wp[0] + wp[1] + wp[2] + wp[3]) * (1.0f / (float)N_ELEMS);
}

extern "C" void kernel_launch(void* const* d_in, const int* in_sizes, int n_in,
                              void* d_out, int out_size, void* d_ws, size_t ws_size,
                              hipStream_t stream) {
    const float* img1 = (const float*)d_in[0];
    const float* img2 = (const float*)d_in[1];
    float* out = (float*)d_out;
    float* partials = (float*)d_ws;     // NBLK floats = 30.7 KB

    ssim_main<<<NBLK, NTHREADS, 0, stream>>>(img1, img2, partials);
    ssim_final<<<1, NTHREADS, 0, stream>>>(partials, out);
}